// Round 11
// baseline (202.829 us; speedup 1.0000x reference)
//
#include <hip/hip_runtime.h>
#include <math.h>

#define KC 33            // clusters
#define ED 32            // embedding dim
#define KE (KC * ED)     // 1056
#define PAD 33           // padded leading dim for LDS tiles

#define BPB_A 128        // accum blocks per batch (grid 1024)
#define BPB_H 128        // hinge blocks per batch (grid 1024)
#define QD 264           // KE/4: dims per k_centers block

// ws layout (floats), all written-before-read (no zero pass, no global atomics
// except the 8 out-adds): psums[1024*KE] | pcnt[B*KC*128] | pvar[1024] |
// centers[B*KE] | counts[B*KC]

// Pass 1 rebuilt for LDS-op count + occupancy: priv copies 8->4 (per-wave)
// with ds_add_f32 (atomicAdd on LDS; bank=e conflict-free, cross-half-wave
// same-address only when labels match: 1/33, atomic-serialized), packed b64
// label reads (1 op vs 4 broadcasts), loads software-pipelined 8 deep in
// NAMED regs (runtime-indexed arrays would spill to scratch). ~10 LDS
// wave-instrs/group vs r8's ~17; LDS 39 -> 22.5 KB -> 7 blocks/CU (28 w/CU).
#define ABODY(creg, g) do {                                                  \
    {   float* d = &strip[(l5 >> 3) * PAD + (l5 & 7) * 4];                   \
        d[0] = (creg).x; d[1] = (creg).y; d[2] = (creg).z; d[3] = (creg).w; }\
    unsigned long long lv =                                                  \
        *(const unsigned long long*)&s_lab[w * 128 + (g) * 8 + h * 4];       \
    int k0 = (int)(lv & 0xFFFFull);                                          \
    int k1 = (int)((lv >> 16) & 0xFFFFull);                                  \
    int k2 = (int)((lv >> 32) & 0xFFFFull);                                  \
    int k3 = (int)((lv >> 48) & 0xFFFFull);                                  \
    atomicAdd(&priv[k0 * ED + l5], strip[0 * PAD + l5]);                     \
    atomicAdd(&priv[k1 * ED + l5], strip[1 * PAD + l5]);                     \
    atomicAdd(&priv[k2 * ED + l5], strip[2 * PAD + l5]);                     \
    atomicAdd(&priv[k3 * ED + l5], strip[3 * PAD + l5]);                     \
} while (0)

__global__ __launch_bounds__(256) void k_accum(const float* __restrict__ emb,
                                               const int* __restrict__ lab,
                                               float* __restrict__ psums,
                                               float* __restrict__ pcnt, int N) {
    __shared__ float s_stage[8 * 4 * PAD];       // 4.2 KB: 8 half-wave strips
    __shared__ float s_priv[4 * KE];             // 16.9 KB: per-WAVE copies
    __shared__ unsigned short s_lab[512];
    __shared__ float s_hist[2 * KC];
    int t = threadIdx.x;
    int bid   = blockIdx.x;
    int b     = bid / BPB_A;
    int blk   = bid % BPB_A;
    int chunk = N / BPB_A;                       // 512
    int s  = t >> 5;                             // half-wave slot 0..7
    int w  = t >> 6;
    int h  = (t >> 5) & 1;
    int l5 = t & 31;
    size_t pbase = (size_t)b * N + (size_t)blk * chunk;
    const float4* g4 = (const float4*)(emb + pbase * ED);

    for (int i = t; i < 4 * KE; i += 256) s_priv[i] = 0.f;
    if (t < 2 * KC) s_hist[t] = 0.f;

    int2 lp = ((const int2*)(lab + pbase))[t];
    s_lab[2 * t]     = (unsigned short)lp.x;
    s_lab[2 * t + 1] = (unsigned short)lp.y;
    __syncthreads();                             // the only barrier before flush
    {
        float* hh = &s_hist[(t >> 7) * KC];
        atomicAdd(&hh[lp.x], 1.f);
        atomicAdd(&hh[lp.y], 1.f);
    }

    float* strip = &s_stage[s * 4 * PAD];
    float* priv  = &s_priv[w * KE];
    int fbase = w * 1024 + h * 32 + l5;          // float4 idx: + g*64

    // depth-8 software pipeline, named regs only
    float4 c0 = g4[fbase],       c1 = g4[fbase + 64],  c2 = g4[fbase + 128],
           c3 = g4[fbase + 192], c4 = g4[fbase + 256], c5 = g4[fbase + 320],
           c6 = g4[fbase + 384], c7 = g4[fbase + 448];
    ABODY(c0, 0);  c0 = g4[fbase + 512];
    ABODY(c1, 1);  c1 = g4[fbase + 576];
    ABODY(c2, 2);  c2 = g4[fbase + 640];
    ABODY(c3, 3);  c3 = g4[fbase + 704];
    ABODY(c4, 4);  c4 = g4[fbase + 768];
    ABODY(c5, 5);  c5 = g4[fbase + 832];
    ABODY(c6, 6);  c6 = g4[fbase + 896];
    ABODY(c7, 7);  c7 = g4[fbase + 960];
    ABODY(c0, 8);  ABODY(c1, 9);  ABODY(c2, 10); ABODY(c3, 11);
    ABODY(c4, 12); ABODY(c5, 13); ABODY(c6, 14); ABODY(c7, 15);
    __syncthreads();

    // flush: plain coalesced stores of this block's partials
    for (int i = t; i < KE; i += 256) {
        float v = 0.f;
#pragma unroll
        for (int c = 0; c < 4; c++) v += s_priv[c * KE + i];
        psums[(size_t)bid * KE + i] = v;
    }
    if (t < KC)
        pcnt[((size_t)b * KC + t) * BPB_A + blk] = s_hist[t] + s_hist[KC + t];
}

// Reduce 128 partials/batch -> centers (divided) + counts; block 0 also
// zeroes out[0] (k_zero and k_out both deleted -> 4 launches total).
__global__ __launch_bounds__(256) void k_centers(const float* __restrict__ psums,
                                                 const float* __restrict__ pcnt,
                                                 float* __restrict__ centers,
                                                 float* __restrict__ counts,
                                                 float* __restrict__ out) {
    __shared__ float s_cnt[KC];
    int t = threadIdx.x;
    int b = blockIdx.x >> 2;
    int q = blockIdx.x & 3;
    if (blockIdx.x == 0 && t == 0) out[0] = 0.f;
    if (t < KC) {
        const float4* p4 = (const float4*)(pcnt + ((size_t)b * KC + t) * BPB_A);
        float c = 0.f;
        for (int u = 0; u < BPB_A / 4; u++) {
            float4 v = p4[u];
            c += (v.x + v.y) + (v.z + v.w);      // exact: small integers
        }
        s_cnt[t] = c;
        if (q == 0) counts[b * KC + t] = c;
    }
    __syncthreads();
    for (int il = t; il < QD; il += 256) {
        int i = q * QD + il;
        const float* ps = psums + (size_t)b * BPB_A * KE + i;
        float acc = 0.f;
        for (int blk = 0; blk < BPB_A; blk++) acc += ps[(size_t)blk * KE];
        centers[(size_t)b * KE + i] = acc / fmaxf(s_cnt[i >> 5], 1.f);
    }
}

// Pass 2: lane-owns-point hinge, wave-private 64-row strips. UNCHANGED from
// r10 (measured: below the 40us fills).
__global__ __launch_bounds__(256) void k_hinge(const float* __restrict__ emb,
                                               const int* __restrict__ lab,
                                               const float* __restrict__ centers,
                                               const float* __restrict__ counts,
                                               float* __restrict__ pvar, int N) {
    __shared__ float s_wtile[4 * 64 * PAD];      // 33.8 KB: 4 wave strips
    __shared__ float s_ctr[KC * PAD];            // 4.3 KB padded centers
    __shared__ float s_inv[KC];
    __shared__ unsigned short s_lab[512];
    __shared__ float s_red[4];
    int t = threadIdx.x;
    int b     = blockIdx.x / BPB_H;
    int blk   = blockIdx.x % BPB_H;
    int chunk = N / BPB_H;                       // 512
    int w = t >> 6, l = t & 63;
    size_t pbase = (size_t)b * N + (size_t)blk * chunk;
    const float4* g4 = (const float4*)(emb + pbase * ED);

    int2 lp = ((const int2*)(lab + pbase))[t];
    s_lab[2 * t]     = (unsigned short)lp.x;
    s_lab[2 * t + 1] = (unsigned short)lp.y;

    if (t < KC) {
        float c = counts[b * KC + t];
        s_inv[t] = (t > 0 && c > 0.f) ? 1.f / fmaxf(c, 1.f) : 0.f;
    }
    for (int i = t; i < KE; i += 256) {
        int k = i >> 5, e = i & 31;
        s_ctr[k * PAD + e] = centers[(size_t)b * KE + i];
    }
    __syncthreads();                             // ctr+inv+labels ready

    float* strip = &s_wtile[w * 64 * PAD];
    int fb = w * 1024 + l;
    float4 r0 = g4[fb],       r1 = g4[fb + 64],  r2 = g4[fb + 128], r3 = g4[fb + 192];
    float4 r4 = g4[fb + 256], r5 = g4[fb + 320], r6 = g4[fb + 384], r7 = g4[fb + 448];

    float hs = 0.f;
    for (int g = 0; g < 2; g++) {
        {   // unpack 8 regs into wave strip
            int f, p, m;
            f = l;        p = f >> 3; m = (f & 7) * 4;
            { float* d = &strip[PAD * p + m]; d[0]=r0.x; d[1]=r0.y; d[2]=r0.z; d[3]=r0.w; }
            f = l + 64;   p = f >> 3; m = (f & 7) * 4;
            { float* d = &strip[PAD * p + m]; d[0]=r1.x; d[1]=r1.y; d[2]=r1.z; d[3]=r1.w; }
            f = l + 128;  p = f >> 3; m = (f & 7) * 4;
            { float* d = &strip[PAD * p + m]; d[0]=r2.x; d[1]=r2.y; d[2]=r2.z; d[3]=r2.w; }
            f = l + 192;  p = f >> 3; m = (f & 7) * 4;
            { float* d = &strip[PAD * p + m]; d[0]=r3.x; d[1]=r3.y; d[2]=r3.z; d[3]=r3.w; }
            f = l + 256;  p = f >> 3; m = (f & 7) * 4;
            { float* d = &strip[PAD * p + m]; d[0]=r4.x; d[1]=r4.y; d[2]=r4.z; d[3]=r4.w; }
            f = l + 320;  p = f >> 3; m = (f & 7) * 4;
            { float* d = &strip[PAD * p + m]; d[0]=r5.x; d[1]=r5.y; d[2]=r5.z; d[3]=r5.w; }
            f = l + 384;  p = f >> 3; m = (f & 7) * 4;
            { float* d = &strip[PAD * p + m]; d[0]=r6.x; d[1]=r6.y; d[2]=r6.z; d[3]=r6.w; }
            f = l + 448;  p = f >> 3; m = (f & 7) * 4;
            { float* d = &strip[PAD * p + m]; d[0]=r7.x; d[1]=r7.y; d[2]=r7.z; d[3]=r7.w; }
        }
        if (g + 1 < 2) {
            int nb = fb + 512;
            r0 = g4[nb];       r1 = g4[nb + 64];  r2 = g4[nb + 128]; r3 = g4[nb + 192];
            r4 = g4[nb + 256]; r5 = g4[nb + 320]; r6 = g4[nb + 384]; r7 = g4[nb + 448];
        }

        int   k  = (int)s_lab[w * 128 + g * 64 + l];
        float iv = s_inv[k];
        const float* xr = &strip[l * PAD];
        const float* cr = &s_ctr[k * PAD];
        float d2 = 0.f;
#pragma unroll
        for (int j = 0; j < ED; j++) {
            float d = xr[j] - cr[j];
            d2 = fmaf(d, d, d2);
        }
        float dist = sqrtf(fmaxf(d2, 1e-12f));
        hs += fmaxf(dist - 0.5f, 0.f) * iv;
    }

    hs += __shfl_xor(hs, 1);  hs += __shfl_xor(hs, 2);  hs += __shfl_xor(hs, 4);
    hs += __shfl_xor(hs, 8);  hs += __shfl_xor(hs, 16); hs += __shfl_xor(hs, 32);
    if ((t & 63) == 0) s_red[t >> 6] = hs;
    __syncthreads();
    if (t == 0)
        pvar[blockIdx.x] = s_red[0] + s_red[1] + s_red[2] + s_red[3];
}

// Epilogue: 8 blocks, one per batch; atomicAdd of pb/B into out (zeroed by
// k_centers block 0 upstream in the stream).
__global__ __launch_bounds__(256) void k_final(const float* __restrict__ centers,
                                               const float* __restrict__ counts,
                                               const float* __restrict__ pvar,
                                               float* __restrict__ out) {
    __shared__ float s_ctr[KE];
    __shared__ float s_reg[KC];
    __shared__ int   s_prs[KC];
    __shared__ float s_red[256];
    int b = blockIdx.x;
    int t = threadIdx.x;

    float vp = (t < BPB_H) ? pvar[b * BPB_H + t] : 0.f;
    if (t < KC) {
        float c = counts[b * KC + t];
        s_prs[t] = (t > 0 && c > 0.f) ? 1 : 0;
    }
    for (int i = t; i < KE; i += 256)
        s_ctr[i] = centers[(size_t)b * KE + i];
    __syncthreads();
    if (t < KC) {
        float n2 = 0.f;
        for (int e2 = 0; e2 < ED; e2++) { float c = s_ctr[t * ED + e2]; n2 += c * c; }
        s_reg[t] = s_prs[t] ? sqrtf(fmaxf(n2, 1e-12f)) : 0.f;
    }
    s_red[t] = vp;
    __syncthreads();
    for (int s = 128; s > 0; s >>= 1) {
        if (t < s) s_red[t] += s_red[t + s];
        __syncthreads();
    }
    float var_b = s_red[0];
    __syncthreads();

    float psum = 0.f;
    for (int q = t; q < KC * KC; q += 256) {
        int i = q / KC, j = q % KC;
        if (i < j && s_prs[i] && s_prs[j]) {
            float d2 = 0.f;
            for (int e2 = 0; e2 < ED; e2++) {
                float d = s_ctr[i * ED + e2] - s_ctr[j * ED + e2];
                d2 += d * d;
            }
            float cd = sqrtf(fmaxf(d2, 1e-12f));
            psum += fmaxf(3.0f - cd, 0.f);   // 2*DELTA_D = 3.0
        }
    }
    s_red[t] = psum;
    __syncthreads();
    for (int s = 128; s > 0; s >>= 1) {
        if (t < s) s_red[t] += s_red[t + s];
        __syncthreads();
    }

    if (t == 0) {
        float reg = 0.f; int n = 0;
        for (int k = 0; k < KC; k++) { reg += s_reg[k]; n += s_prs[k]; }
        float nf = (float)n;
        float variance_term = var_b / fmaxf(nf, 1.f);
        float npairs = nf * (nf - 1.f) * 0.5f;
        float distance_term = s_red[0] / fmaxf(npairs, 1.f);
        float reg_term = reg / fmaxf(nf, 1.f);
        float pb = variance_term + distance_term + 0.001f * reg_term;
        if (n == 0) pb = 0.f;
        atomicAdd(out, pb * 0.125f);         // / B
    }
}

extern "C" void kernel_launch(void* const* d_in, const int* in_sizes, int n_in,
                              void* d_out, int out_size, void* d_ws, size_t ws_size,
                              hipStream_t stream) {
    const float* emb = (const float*)d_in[0];
    const int*   lab = (const int*)d_in[1];
    float* out = (float*)d_out;

    const int B = 8;
    const int N = in_sizes[1] / B;   // 65536

    float* psums   = (float*)d_ws;                         // 1024*KE
    float* pcnt    = psums + (size_t)B * BPB_A * KE;       // B*KC*128
    float* pvar    = pcnt + (size_t)B * KC * BPB_A;        // 1024
    float* centers = pvar + (size_t)B * BPB_H;             // B*KE
    float* counts  = centers + (size_t)B * KE;             // B*KC

    k_accum<<<B * BPB_A, 256, 0, stream>>>(emb, lab, psums, pcnt, N);
    k_centers<<<B * 4, 256, 0, stream>>>(psums, pcnt, centers, counts, out);
    k_hinge<<<B * BPB_H, 256, 0, stream>>>(emb, lab, centers, counts, pvar, N);
    k_final<<<B, 256, 0, stream>>>(centers, counts, pvar, out);
}

// Round 12
// 128.154 us; speedup vs baseline: 1.5827x; 1.5827x over previous
//
#include <hip/hip_runtime.h>
#include <math.h>

#define KC 33            // clusters
#define ED 32            // embedding dim
#define KE (KC * ED)     // 1056
#define PAD 33           // padded leading dim for LDS tiles

#define BPB_A 128        // accum blocks per batch (grid 1024)
#define BPB_H 128        // hinge blocks per batch (grid 1024)
#define QD 264           // KE/4: dims per k_centers block

// ws layout (floats), all written-before-read (no zero pass; only atomics are
// the 8 out-adds): psums[1024*KE] | pcnt[B*KC*128] | pvar[1024] |
// centers[B*KE] | counts[B*KC]

// Pass 1: per-block partial sums + label histogram, barrier-free half-wave
// strips, ordered read-add-write into per-half-wave private copies, depth-2
// prefetch. VERBATIM r10 body (measured ~20us; r11's LDS-atomic + depth-8
// variant collapsed to VGPR=36 and ran 93us -- reverted).
__global__ __launch_bounds__(256) void k_accum(const float* __restrict__ emb,
                                               const int* __restrict__ lab,
                                               float* __restrict__ psums,
                                               float* __restrict__ pcnt, int N) {
    __shared__ float s_stage[8 * 4 * PAD];       // 4.2 KB: 8 half-wave strips
    __shared__ float s_priv[8 * KE];             // 33.8 KB private sum copies
    __shared__ unsigned short s_lab[512];
    __shared__ float s_hist[2 * KC];
    int t = threadIdx.x;
    int bid   = blockIdx.x;
    int b     = bid / BPB_A;
    int blk   = bid % BPB_A;
    int chunk = N / BPB_A;                       // 512
    int e  = t & 31;
    int s  = t >> 5;                             // half-wave slot 0..7
    int w  = t >> 6;
    int h  = (t >> 5) & 1;
    int l5 = t & 31;
    size_t pbase = (size_t)b * N + (size_t)blk * chunk;
    const float4* g4 = (const float4*)(emb + pbase * ED);

    for (int i = t; i < 8 * KE; i += 256) s_priv[i] = 0.f;
    if (t < 2 * KC) s_hist[t] = 0.f;

    int2 lp = ((const int2*)(lab + pbase))[t];
    s_lab[2 * t]     = (unsigned short)lp.x;
    s_lab[2 * t + 1] = (unsigned short)lp.y;
    __syncthreads();                             // the only barrier before flush
    {
        float* hh = &s_hist[(t >> 7) * KC];
        atomicAdd(&hh[lp.x], 1.f);
        atomicAdd(&hh[lp.y], 1.f);
    }

    float* strip = &s_stage[s * 4 * PAD];
    float* priv  = &s_priv[s * KE];
    int fbase = w * 1024 + h * 32 + l5;          // float4 idx: + g*64
    float4 c0 = g4[fbase];
    float4 c1 = g4[fbase + 64];
    for (int g = 0; g < 16; g++) {
        {   // stage this half-wave's 4 points
            float* d = &strip[(l5 >> 3) * PAD + (l5 & 7) * 4];
            d[0] = c0.x; d[1] = c0.y; d[2] = c0.z; d[3] = c0.w;
        }
        float4 c2;
        if (g + 2 < 16) c2 = g4[fbase + (g + 2) * 64];   // depth-2 prefetch
        int lbase = w * 128 + g * 8 + h * 4;
#pragma unroll
        for (int j = 0; j < 4; j++) {
            float x = strip[j * PAD + e];        // bank (4s+j+e)%32: free
            int   k = (int)s_lab[lbase + j];     // broadcast within half-wave
            priv[k * ED + e] += x;               // private; bank=e: free
        }
        c0 = c1; c1 = c2;
    }
    __syncthreads();

    // flush: plain coalesced stores of this block's partials (no atomics)
    for (int i = t; i < KE; i += 256) {
        float v = 0.f;
#pragma unroll
        for (int c = 0; c < 8; c++) v += s_priv[c * KE + i];
        psums[(size_t)bid * KE + i] = v;
    }
    if (t < KC)
        pcnt[((size_t)b * KC + t) * BPB_A + blk] = s_hist[t] + s_hist[KC + t];
}

// Reduce 128 partials/batch -> centers (divided) + counts; block 0 also zeroes
// out[0] (runs before k_final in-stream; k_zero and k_out deleted -> 4 launches).
__global__ __launch_bounds__(256) void k_centers(const float* __restrict__ psums,
                                                 const float* __restrict__ pcnt,
                                                 float* __restrict__ centers,
                                                 float* __restrict__ counts,
                                                 float* __restrict__ out) {
    __shared__ float s_cnt[KC];
    int t = threadIdx.x;
    int b = blockIdx.x >> 2;
    int q = blockIdx.x & 3;
    if (blockIdx.x == 0 && t == 0) out[0] = 0.f;
    if (t < KC) {
        const float4* p4 = (const float4*)(pcnt + ((size_t)b * KC + t) * BPB_A);
        float c = 0.f;
        for (int u = 0; u < BPB_A / 4; u++) {
            float4 v = p4[u];
            c += (v.x + v.y) + (v.z + v.w);      // exact: small integers
        }
        s_cnt[t] = c;
        if (q == 0) counts[b * KC + t] = c;
    }
    __syncthreads();
    for (int il = t; il < QD; il += 256) {
        int i = q * QD + il;
        const float* ps = psums + (size_t)b * BPB_A * KE + i;
        float acc = 0.f;
        for (int blk = 0; blk < BPB_A; blk++) acc += ps[(size_t)blk * KE];
        centers[(size_t)b * KE + i] = acc / fmaxf(s_cnt[i >> 5], 1.f);
    }
}

// Pass 2: lane-owns-point hinge, wave-private 64-row strips. VERBATIM r10 body.
__global__ __launch_bounds__(256) void k_hinge(const float* __restrict__ emb,
                                               const int* __restrict__ lab,
                                               const float* __restrict__ centers,
                                               const float* __restrict__ counts,
                                               float* __restrict__ pvar, int N) {
    __shared__ float s_wtile[4 * 64 * PAD];      // 33.8 KB: 4 wave strips
    __shared__ float s_ctr[KC * PAD];            // 4.3 KB padded centers
    __shared__ float s_inv[KC];
    __shared__ unsigned short s_lab[512];
    __shared__ float s_red[4];
    int t = threadIdx.x;
    int b     = blockIdx.x / BPB_H;
    int blk   = blockIdx.x % BPB_H;
    int chunk = N / BPB_H;                       // 512
    int w = t >> 6, l = t & 63;
    size_t pbase = (size_t)b * N + (size_t)blk * chunk;
    const float4* g4 = (const float4*)(emb + pbase * ED);

    int2 lp = ((const int2*)(lab + pbase))[t];
    s_lab[2 * t]     = (unsigned short)lp.x;
    s_lab[2 * t + 1] = (unsigned short)lp.y;

    if (t < KC) {
        float c = counts[b * KC + t];
        s_inv[t] = (t > 0 && c > 0.f) ? 1.f / fmaxf(c, 1.f) : 0.f;
    }
    for (int i = t; i < KE; i += 256) {
        int k = i >> 5, e = i & 31;
        s_ctr[k * PAD + e] = centers[(size_t)b * KE + i];
    }
    __syncthreads();                             // ctr+inv+labels ready

    float* strip = &s_wtile[w * 64 * PAD];
    int fb = w * 1024 + l;
    float4 r0 = g4[fb],       r1 = g4[fb + 64],  r2 = g4[fb + 128], r3 = g4[fb + 192];
    float4 r4 = g4[fb + 256], r5 = g4[fb + 320], r6 = g4[fb + 384], r7 = g4[fb + 448];

    float hs = 0.f;
    for (int g = 0; g < 2; g++) {
        {   // unpack 8 regs into wave strip
            int f, p, m;
            f = l;        p = f >> 3; m = (f & 7) * 4;
            { float* d = &strip[PAD * p + m]; d[0]=r0.x; d[1]=r0.y; d[2]=r0.z; d[3]=r0.w; }
            f = l + 64;   p = f >> 3; m = (f & 7) * 4;
            { float* d = &strip[PAD * p + m]; d[0]=r1.x; d[1]=r1.y; d[2]=r1.z; d[3]=r1.w; }
            f = l + 128;  p = f >> 3; m = (f & 7) * 4;
            { float* d = &strip[PAD * p + m]; d[0]=r2.x; d[1]=r2.y; d[2]=r2.z; d[3]=r2.w; }
            f = l + 192;  p = f >> 3; m = (f & 7) * 4;
            { float* d = &strip[PAD * p + m]; d[0]=r3.x; d[1]=r3.y; d[2]=r3.z; d[3]=r3.w; }
            f = l + 256;  p = f >> 3; m = (f & 7) * 4;
            { float* d = &strip[PAD * p + m]; d[0]=r4.x; d[1]=r4.y; d[2]=r4.z; d[3]=r4.w; }
            f = l + 320;  p = f >> 3; m = (f & 7) * 4;
            { float* d = &strip[PAD * p + m]; d[0]=r5.x; d[1]=r5.y; d[2]=r5.z; d[3]=r5.w; }
            f = l + 384;  p = f >> 3; m = (f & 7) * 4;
            { float* d = &strip[PAD * p + m]; d[0]=r6.x; d[1]=r6.y; d[2]=r6.z; d[3]=r6.w; }
            f = l + 448;  p = f >> 3; m = (f & 7) * 4;
            { float* d = &strip[PAD * p + m]; d[0]=r7.x; d[1]=r7.y; d[2]=r7.z; d[3]=r7.w; }
        }
        if (g + 1 < 2) {
            int nb = fb + 512;
            r0 = g4[nb];       r1 = g4[nb + 64];  r2 = g4[nb + 128]; r3 = g4[nb + 192];
            r4 = g4[nb + 256]; r5 = g4[nb + 320]; r6 = g4[nb + 384]; r7 = g4[nb + 448];
        }

        int   k  = (int)s_lab[w * 128 + g * 64 + l];
        float iv = s_inv[k];
        const float* xr = &strip[l * PAD];
        const float* cr = &s_ctr[k * PAD];
        float d2 = 0.f;
#pragma unroll
        for (int j = 0; j < ED; j++) {
            float d = xr[j] - cr[j];
            d2 = fmaf(d, d, d2);
        }
        float dist = sqrtf(fmaxf(d2, 1e-12f));
        hs += fmaxf(dist - 0.5f, 0.f) * iv;
    }

    hs += __shfl_xor(hs, 1);  hs += __shfl_xor(hs, 2);  hs += __shfl_xor(hs, 4);
    hs += __shfl_xor(hs, 8);  hs += __shfl_xor(hs, 16); hs += __shfl_xor(hs, 32);
    if ((t & 63) == 0) s_red[t >> 6] = hs;
    __syncthreads();
    if (t == 0)
        pvar[blockIdx.x] = s_red[0] + s_red[1] + s_red[2] + s_red[3];
}

// Epilogue: 8 blocks, one per batch; atomicAdd of pb/B into out (zeroed by
// k_centers block 0 upstream in the stream).
__global__ __launch_bounds__(256) void k_final(const float* __restrict__ centers,
                                               const float* __restrict__ counts,
                                               const float* __restrict__ pvar,
                                               float* __restrict__ out) {
    __shared__ float s_ctr[KE];
    __shared__ float s_reg[KC];
    __shared__ int   s_prs[KC];
    __shared__ float s_red[256];
    int b = blockIdx.x;
    int t = threadIdx.x;

    float vp = (t < BPB_H) ? pvar[b * BPB_H + t] : 0.f;
    if (t < KC) {
        float c = counts[b * KC + t];
        s_prs[t] = (t > 0 && c > 0.f) ? 1 : 0;
    }
    for (int i = t; i < KE; i += 256)
        s_ctr[i] = centers[(size_t)b * KE + i];
    __syncthreads();
    if (t < KC) {
        float n2 = 0.f;
        for (int e2 = 0; e2 < ED; e2++) { float c = s_ctr[t * ED + e2]; n2 += c * c; }
        s_reg[t] = s_prs[t] ? sqrtf(fmaxf(n2, 1e-12f)) : 0.f;
    }
    s_red[t] = vp;
    __syncthreads();
    for (int s = 128; s > 0; s >>= 1) {
        if (t < s) s_red[t] += s_red[t + s];
        __syncthreads();
    }
    float var_b = s_red[0];
    __syncthreads();

    float psum = 0.f;
    for (int q = t; q < KC * KC; q += 256) {
        int i = q / KC, j = q % KC;
        if (i < j && s_prs[i] && s_prs[j]) {
            float d2 = 0.f;
            for (int e2 = 0; e2 < ED; e2++) {
                float d = s_ctr[i * ED + e2] - s_ctr[j * ED + e2];
                d2 += d * d;
            }
            float cd = sqrtf(fmaxf(d2, 1e-12f));
            psum += fmaxf(3.0f - cd, 0.f);   // 2*DELTA_D = 3.0
        }
    }
    s_red[t] = psum;
    __syncthreads();
    for (int s = 128; s > 0; s >>= 1) {
        if (t < s) s_red[t] += s_red[t + s];
        __syncthreads();
    }

    if (t == 0) {
        float reg = 0.f; int n = 0;
        for (int k = 0; k < KC; k++) { reg += s_reg[k]; n += s_prs[k]; }
        float nf = (float)n;
        float variance_term = var_b / fmaxf(nf, 1.f);
        float npairs = nf * (nf - 1.f) * 0.5f;
        float distance_term = s_red[0] / fmaxf(npairs, 1.f);
        float reg_term = reg / fmaxf(nf, 1.f);
        float pb = variance_term + distance_term + 0.001f * reg_term;
        if (n == 0) pb = 0.f;
        atomicAdd(out, pb * 0.125f);         // / B
    }
}

extern "C" void kernel_launch(void* const* d_in, const int* in_sizes, int n_in,
                              void* d_out, int out_size, void* d_ws, size_t ws_size,
                              hipStream_t stream) {
    const float* emb = (const float*)d_in[0];
    const int*   lab = (const int*)d_in[1];
    float* out = (float*)d_out;

    const int B = 8;
    const int N = in_sizes[1] / B;   // 65536

    float* psums   = (float*)d_ws;                         // 1024*KE
    float* pcnt    = psums + (size_t)B * BPB_A * KE;       // B*KC*128
    float* pvar    = pcnt + (size_t)B * KC * BPB_A;        // 1024
    float* centers = pvar + (size_t)B * BPB_H;             // B*KE
    float* counts  = centers + (size_t)B * KE;             // B*KC

    k_accum<<<B * BPB_A, 256, 0, stream>>>(emb, lab, psums, pcnt, N);
    k_centers<<<B * 4, 256, 0, stream>>>(psums, pcnt, centers, counts, out);
    k_hinge<<<B * BPB_H, 256, 0, stream>>>(emb, lab, centers, counts, pvar, N);
    k_final<<<B, 256, 0, stream>>>(centers, counts, pvar, out);
}